// Round 9
// baseline (174.183 us; speedup 1.0000x reference)
//
#include <hip/hip_runtime.h>

// Problem: B=2048, D=2048, N=64 transforms, R=32.
//  out0 (2048x2048 f32) = sum_n gate[b,n] * (x V_n^T U_n^T)
//  out1 (2048x64  f32) = jumprelu(x enc^T - bias)
//  out2 (64 f32)       = ||U_n||_F ||V_n||_F / 256
// R8->R9: R8 (TEAMS=4, 128KB LDS, 1 blk/CU) regressed: barrier drains had
// no sibling block to hide behind. Rules: keep 2 blocks/CU.
// (1) gate GEMM folded into GEMM1: B = [Vflat; enc] (2112 rows); EPI emits
//     raw-Y bf16 (col<2048) and gate=relu(acc-bias) (col>=2048, = out1).
//     In-place k_gate_apply then does Y *= gate.
// (2) GEMM2: 128x128 TEAMS=2 grid-split-K x2 (512 blocks, 64KB LDS,
//     2 blk/CU) -> staged traffic 402->268 MB; bf16 partials into dead
//     xb/VbEnc regions; k_out_reduce sums them. No atomics.

#define D_MODEL 2048
#define BATCH   2048
#define NT      64
#define RANK    32
#define NBV     2048   // V-columns in merged B (enc occupies [2048,2112))

typedef __attribute__((ext_vector_type(8))) __bf16 bf16x8;
typedef __attribute__((ext_vector_type(4))) float  f32x4;

__device__ __forceinline__ unsigned short f2bf(float f) {
  unsigned int u = __builtin_bit_cast(unsigned int, f);
  u += 0x7FFFu + ((u >> 16) & 1u);          // RNE
  return (unsigned short)(u >> 16);
}
__device__ __forceinline__ float bf2f(unsigned short h) {
  unsigned int u = (unsigned int)h << 16;
  return __builtin_bit_cast(float, u);
}

// async global->LDS, 16B per lane. LDS dest is wave-uniform base + lane*16.
__device__ __forceinline__ void gload_lds16(const void* g, void* l) {
  __builtin_amdgcn_global_load_lds(
      (const __attribute__((address_space(1))) unsigned int*)g,
      (__attribute__((address_space(3))) unsigned int*)l,
      16, 0, 0);
}

// ---------------- merged prep ----------------
// blocks [0,1024): x->bf16   [1024,1152): enc->VbEnc rows [2048,2112)
// blocks [1152,1408): V->VbEnc rows [0,2048) (+sumsq)
// blocks [1408,1664): U->Ut bf16 (+sumsq)

__device__ __forceinline__ void block_reduce_store(float ss, float* dst, int slot) {
  __shared__ float red[256];
  int t = threadIdx.x;
  red[t] = ss;
  __syncthreads();
  for (int s = 128; s > 0; s >>= 1) {
    if (t < s) red[t] += red[t + s];
    __syncthreads();
  }
  if (t == 0) dst[slot] = red[0];
}

__global__ void k_prep(const float4* __restrict__ x, const float4* __restrict__ enc,
                       const float4* __restrict__ V, const float4* __restrict__ U,
                       ushort4* __restrict__ xb, ushort4* __restrict__ VbEnc,
                       unsigned short* __restrict__ Ut,
                       float* __restrict__ partV, float* __restrict__ partU) {
  int bid = blockIdx.x, t = threadIdx.x;
  if (bid < 1024) {                      // x: 1048576 float4, 1024 per block
#pragma unroll
    for (int it = 0; it < 4; ++it) {
      int i = bid * 1024 + it * 256 + t;
      float4 v = x[i];
      ushort4 o;
      o.x = f2bf(v.x); o.y = f2bf(v.y); o.z = f2bf(v.z); o.w = f2bf(v.w);
      xb[i] = o;
    }
  } else if (bid < 1152) {               // enc: 32768 float4 -> rows 2048+
    int i = (bid - 1024) * 256 + t;
    float4 v = enc[i];
    ushort4 o;
    o.x = f2bf(v.x); o.y = f2bf(v.y); o.z = f2bf(v.z); o.w = f2bf(v.w);
    VbEnc[1048576 + i] = o;              // 2048*2048/4 offset
  } else if (bid < 1408) {               // V: contiguous convert + sumsq
    int b = bid - 1152;
    size_t base4 = (size_t)b * 4096;
    float ss = 0.f;
    for (int it = 0; it < 16; ++it) {
      size_t idx = base4 + t + it * 256;
      float4 v = V[idx];
      ss += v.x * v.x + v.y * v.y + v.z * v.z + v.w * v.w;
      ushort4 o;
      o.x = f2bf(v.x); o.y = f2bf(v.y); o.z = f2bf(v.z); o.w = f2bf(v.w);
      VbEnc[idx] = o;
    }
    block_reduce_store(ss, partV, b);
  } else {                               // U: transpose-convert + sumsq
    int b = bid - 1408;
    int n = b >> 2;
    size_t base4 = (size_t)b * 4096;
    float ss = 0.f;
    for (int it = 0; it < 16; ++it) {
      size_t idx4 = base4 + t + it * 256;
      float4 v = U[idx4];
      ss += v.x * v.x + v.y * v.y + v.z * v.z + v.w * v.w;
      size_t e = idx4 * 4 - (size_t)n * (D_MODEL * RANK);
      int dcol = (int)(e >> 5);
      int r = (int)(e & 31);
      ushort4 o;
      o.x = f2bf(v.x); o.y = f2bf(v.y); o.z = f2bf(v.z); o.w = f2bf(v.w);
      *(ushort4*)(Ut + (size_t)dcol * 2048 + n * 32 + r) = o;
    }
    block_reduce_store(ss, partU, b);
  }
}

// in-place Y *= gate (bf16), + Frobenius finish in block 0
__global__ void k_gate_apply(ushort4* __restrict__ Y, const float* __restrict__ gate,
                             const float* __restrict__ pU, const float* __restrict__ pV,
                             float* __restrict__ frob) {
  int t = threadIdx.x;
  if (blockIdx.x == 0 && t < NT) {
    float su = pU[4 * t] + pU[4 * t + 1] + pU[4 * t + 2] + pU[4 * t + 3];
    float sv = pV[4 * t] + pV[4 * t + 1] + pV[4 * t + 2] + pV[4 * t + 3];
    frob[t] = sqrtf(su) * sqrtf(sv) * (1.0f / 256.0f);
  }
  // 2048*2048 bf16 = 1048576 ushort4 chunks; 1024 blocks * 256 thr * 4
#pragma unroll
  for (int it = 0; it < 4; ++it) {
    int c = blockIdx.x * 1024 + it * 256 + t;   // ushort4 index
    int row = c >> 9;                           // 512 chunks/row
    int n = (c & 511) >> 3;                     // 8 chunks per 32-col group
    float g = gate[row * NT + n];
    ushort4 y = Y[c];
    y.x = f2bf(bf2f(y.x) * g);
    y.y = f2bf(bf2f(y.y) * g);
    y.z = f2bf(bf2f(y.z) * g);
    y.w = f2bf(bf2f(y.w) * g);
    Y[c] = y;
  }
}

// out = f32(P0) + f32(P1)
__global__ void k_out_reduce(const ushort4* __restrict__ P, float4* __restrict__ out) {
#pragma unroll
  for (int it = 0; it < 4; ++it) {
    int c = blockIdx.x * 1024 + it * 256 + threadIdx.x;   // ushort4 index
    ushort4 a = P[c];
    ushort4 b = P[c + 1048576];
    float4 o;
    o.x = bf2f(a.x) + bf2f(b.x);
    o.y = bf2f(a.y) + bf2f(b.y);
    o.z = bf2f(a.z) + bf2f(b.z);
    o.w = bf2f(a.w) + bf2f(b.w);
    out[c] = o;
  }
}

// ---------------- GEMM (BK=64, XOR-swizzled LDS, wave-split-K teams) ------
// A: M x K row-major bf16. Bt: NB x K row-major bf16. TEAMS*256 threads,
// 4 waves per team; team t covers [kbeg + t*klen/TEAMS, +span); TEAMS=2
// accumulators LDS-reduced into team0.
// SWZ=2: grid(256,1,Z): 16x16 tiles, lin%8=XCD block; kbeg=z*klen.
// SWZ=3: grid 528: xcd=lin&7 -> blockM=xcd*2+(i&1), blockN=i>>1 (33 N-tiles).
// EPI 2 (gemm1 merged): col<NBV -> outB[row*2048+col]=bf16(acc) raw;
//        col>=NBV -> g=relu(acc-aux[col-NBV]); outF[row*64+(col-NBV)]=g.
// EPI 5 (gemm2 partial): outB[z*4M + row*2048+col] = bf16(acc).
template <int WGM, int WGN, int MI, int NJ, int EPI, int SWZ, int TEAMS>
__global__ __launch_bounds__(TEAMS * 256, 4)
void gemm_bt(const unsigned short* __restrict__ A,
             const unsigned short* __restrict__ Bt,
             const float* __restrict__ aux,
             unsigned short* __restrict__ outB,
             float* __restrict__ outF, int K, int klen) {
  constexpr int BM = WGM * MI * 16;
  constexpr int BN = WGN * NJ * 16;
  constexpr int RA = BM / 32;
  constexpr int RB = BN / 32;
  __shared__ __align__(16) unsigned short smem[TEAMS * (BM + BN) * 64];

  const int tid = threadIdx.x;
  const int w = tid >> 6;
  const int lane = tid & 63;
  const int quad = lane >> 4;
  const int l15 = lane & 15;
  const int team = w >> 2;               // 4 waves per team
  const int wl = w & 3;
  const int wm = wl % WGM;
  const int wn = wl / WGM;

  unsigned short* As = smem + team * (BM + BN) * 64;
  unsigned short* Bs = As + BM * 64;

  int blockM, blockN, kbeg;
  if constexpr (SWZ == 2) {
    // 256 = 16 (M/128) x 16 (N/128); lin%8 -> XCD; z = split-K half
    const int lin = blockIdx.x;
    const int xcd = lin & 7;
    const int i = lin >> 3;              // 0..31
    blockM = (xcd & 1) * 8 + (i & 7);    // [0,16)
    blockN = (xcd >> 1) * 4 + (i >> 3);  // [0,16)
    kbeg = blockIdx.z * klen;
  } else {  // SWZ == 3
    // 528 = 16 (M/128) x 33 (N/64); per XCD: 2 M-tiles x all 33 N
    const int lin = blockIdx.x;
    const int xcd = lin & 7;
    const int i = lin >> 3;              // 0..65
    blockM = xcd * 2 + (i & 1);          // [0,16)
    blockN = i >> 1;                     // [0,33)
    kbeg = 0;
  }
  const int kspan = klen / TEAMS;
  kbeg += team * kspan;

  // staging: linear LDS slot (row=l>>3, pchunk=l&7) holds logical chunk
  // q = pchunk ^ (row&7)  (XOR swizzle, involutive)
  const int lrow = lane >> 3;
  const int lq = (lane & 7) ^ lrow;
  const unsigned short* Ag = A + (size_t)(blockM * BM + lrow) * K + kbeg + lq * 8;
  const unsigned short* Bg = Bt + (size_t)(blockN * BN + lrow) * K + kbeg + lq * 8;

  // fragment: A[m=l15][k=quad*8+j]; physical chunk = (s*4+quad)^(row&7)
  const int pcs = (quad ^ (lane & 7)) * 16;
  const int rfA = wm * MI * 16 + l15;
  const int rfB = wn * NJ * 16 + l15;

  f32x4 acc[MI][NJ];
  const f32x4 z = {0.f, 0.f, 0.f, 0.f};
#pragma unroll
  for (int i = 0; i < MI; ++i)
#pragma unroll
    for (int j = 0; j < NJ; ++j) acc[i][j] = z;

  for (int k0 = 0; k0 < kspan; k0 += 64) {
#pragma unroll
    for (int j = 0; j < RA; ++j)
      gload_lds16(Ag + (size_t)((j * 4 + wl) * 8) * K + k0,
                  (char*)As + (j * 4 + wl) * 1024);
#pragma unroll
    for (int j = 0; j < RB; ++j)
      gload_lds16(Bg + (size_t)((j * 4 + wl) * 8) * K + k0,
                  (char*)Bs + (j * 4 + wl) * 1024);
    __syncthreads();
#pragma unroll
    for (int s = 0; s < 2; ++s) {
      bf16x8 af[MI], bfr[NJ];
#pragma unroll
      for (int i = 0; i < MI; ++i)
        af[i] = *(const bf16x8*)((const char*)As + (rfA + i * 16) * 128 + (pcs ^ (s << 6)));
#pragma unroll
      for (int j = 0; j < NJ; ++j)
        bfr[j] = *(const bf16x8*)((const char*)Bs + (rfB + j * 16) * 128 + (pcs ^ (s << 6)));
#pragma unroll
      for (int i = 0; i < MI; ++i)
#pragma unroll
        for (int j = 0; j < NJ; ++j)
          acc[i][j] = __builtin_amdgcn_mfma_f32_16x16x32_bf16(af[i], bfr[j], acc[i][j], 0, 0, 0);
    }
    __syncthreads();
  }

  // team reduction through LDS (staging space dead after last barrier)
  float4* red = (float4*)smem;
  const int rslot = ((wl * MI) * NJ) * 64 + lane;
  if (team == 1) {
#pragma unroll
    for (int i = 0; i < MI; ++i)
#pragma unroll
      for (int j = 0; j < NJ; ++j)
        red[rslot + (i * NJ + j) * 64] =
            (float4){acc[i][j][0], acc[i][j][1], acc[i][j][2], acc[i][j][3]};
  }
  __syncthreads();
  if (team == 1) return;
#pragma unroll
  for (int i = 0; i < MI; ++i)
#pragma unroll
    for (int j = 0; j < NJ; ++j) {
      float4 r = red[rslot + (i * NJ + j) * 64];
      acc[i][j][0] += r.x; acc[i][j][1] += r.y;
      acc[i][j][2] += r.z; acc[i][j][3] += r.w;
    }

  // epilogue (team0): C/D layout col=lane&15, row=quad*4+reg
  const int row0 = blockM * BM + wm * MI * 16 + quad * 4;
  const int col0 = blockN * BN + wn * NJ * 16 + l15;
#pragma unroll
  for (int i = 0; i < MI; ++i) {
#pragma unroll
    for (int j = 0; j < NJ; ++j) {
      const int col = col0 + j * 16;
#pragma unroll
      for (int t = 0; t < 4; ++t) {
        const int row = row0 + i * 16 + t;
        float v = acc[i][j][t];
        if constexpr (EPI == 2) {
          if (col < NBV) {
            outB[(size_t)row * 2048 + col] = f2bf(v);          // raw Y
          } else {
            float pre = v - aux[col - NBV];
            outF[(size_t)row * NT + (col - NBV)] = pre > 0.f ? pre : 0.f;
          }
        } else {  // EPI 5: bf16 split-K partial
          outB[(size_t)blockIdx.z * (2048u * 2048u) + (size_t)row * 2048 + col] = f2bf(v);
        }
      }
    }
  }
}

// ---------------- launch ----------------

extern "C" void kernel_launch(void* const* d_in, const int* in_sizes, int n_in,
                              void* d_out, int out_size, void* d_ws, size_t ws_size,
                              hipStream_t stream) {
  const float* x    = (const float*)d_in[0];
  const float* V    = (const float*)d_in[1];
  const float* U    = (const float*)d_in[2];
  const float* enc  = (const float*)d_in[3];
  const float* bias = (const float*)d_in[4];

  float* out  = (float*)d_out;                        // 2048*2048
  float* gate = out + (size_t)BATCH * D_MODEL;        // 2048*64
  float* frob = gate + (size_t)BATCH * NT;            // 64

  // ws layout (~33.2 MB):
  //  [0, 8M):      xb (bf16 x)            -> dead after gemm1 -> P0/P1 partials
  //  [8M, 16.66M): VbEnc (2112x2048 bf16) -> dead after gemm1 (P1 tail)
  //  [17M, 25M):   Ut (bf16)
  //  [25M, 33M):   Y (bf16, raw then gated in-place)
  //  [33M, +2KB):  partU, partV
  char* ws = (char*)d_ws;
  unsigned short* xb    = (unsigned short*)(ws);
  unsigned short* VbEnc = (unsigned short*)(ws + (8u << 20));
  unsigned short* Ut    = (unsigned short*)(ws + (17u << 20));
  unsigned short* Y     = (unsigned short*)(ws + (25u << 20));
  unsigned short* P     = xb;                         // P0 @0, P1 @ +4M elems (16 MB)
  float* partU = (float*)(ws + (33u << 20));
  float* partV = partU + 256;

  // prep: conversions + U transpose + Frobenius partials
  k_prep<<<1664, 256, 0, stream>>>((const float4*)x, (const float4*)enc,
                                   (const float4*)V, (const float4*)U,
                                   (ushort4*)xb, (ushort4*)VbEnc, Ut,
                                   partV, partU);

  // gemm1: [Y | gate] = x @ [Vflat; enc]^T : 2048 x 2112 x 2048
  // 128x64 tiles, TEAMS=2, grid 528 (2 M-tiles x 33 N per XCD)
  gemm_bt<2, 2, 4, 2, 2, 3, 2><<<dim3(528, 1, 1), 512, 0, stream>>>(
      xb, VbEnc, bias, Y, gate, D_MODEL, D_MODEL);

  // Y *= gate (in-place) + frob
  k_gate_apply<<<1024, 256, 0, stream>>>((ushort4*)Y, gate, partU, partV, frob);

  // gemm2: P_z = Y @ Ut^T (K-half z): 128x128, TEAMS=2, grid (256,1,2),
  // 64 KB LDS -> 2 blocks/CU; bf16 partials into dead xb/VbEnc
  gemm_bt<2, 2, 4, 4, 5, 2, 2><<<dim3(256, 1, 2), 512, 0, stream>>>(
      Y, Ut, nullptr, P, nullptr, D_MODEL, 1024);

  // out = f32(P0) + f32(P1)
  k_out_reduce<<<1024, 256, 0, stream>>>((const ushort4*)P, (float4*)out);
}